// Round 1
// baseline (188.835 us; speedup 1.0000x reference)
//
#include <hip/hip_runtime.h>
#include <stdint.h>

typedef __attribute__((ext_vector_type(4))) float fv4;
typedef __attribute__((ext_vector_type(4))) short sv4;
typedef __attribute__((ext_vector_type(8))) short sv8;

#define SCHUNK 2048

static __device__ __forceinline__ short f2bf(float f) {
  union { float f; unsigned u; } v; v.f = f;
  unsigned u = v.u;
  u += 0x7fffu + ((u >> 16) & 1u);   // RNE to bf16
  return (short)(u >> 16);
}

// ---------------- scan: offsets from num_texture ----------------
__global__ __launch_bounds__(256) void scan1(const int* __restrict__ num, int nf,
                                             int* __restrict__ bsum) {
  __shared__ int sd[256];
  int b = blockIdx.x, tid = threadIdx.x;
  int base = b * SCHUNK + tid * 8;
  int s = 0;
#pragma unroll
  for (int j = 0; j < 8; ++j) { int i = base + j; if (i < nf) s += num[i]; }
  sd[tid] = s; __syncthreads();
  for (int st = 128; st > 0; st >>= 1) {
    if (tid < st) sd[tid] += sd[tid + st];
    __syncthreads();
  }
  if (tid == 0) bsum[b] = sd[0];
}

__global__ __launch_bounds__(256) void scan2(int* __restrict__ bsum, int nb) {
  __shared__ int sd[256];
  int tid = threadIdx.x;
  int v = (tid < nb) ? bsum[tid] : 0;
  sd[tid] = v; __syncthreads();
  for (int off = 1; off < 256; off <<= 1) {
    int t = (tid >= off) ? sd[tid - off] : 0;
    __syncthreads();
    sd[tid] += t;
    __syncthreads();
  }
  if (tid < nb) bsum[tid] = sd[tid] - v;   // exclusive prefix
}

__global__ __launch_bounds__(256) void scan3(const int* __restrict__ num, int nf,
                                             const int* __restrict__ bsum,
                                             int* __restrict__ offsets) {
  __shared__ int sc_[256];
  int b = blockIdx.x, tid = threadIdx.x;
  int base = b * SCHUNK + tid * 8;
  int loc[8]; int s = 0;
#pragma unroll
  for (int j = 0; j < 8; ++j) {
    loc[j] = (base + j < nf) ? num[base + j] : 0;
    s += loc[j];
  }
  sc_[tid] = s; __syncthreads();
  for (int off = 1; off < 256; off <<= 1) {
    int t = (tid >= off) ? sc_[tid - off] : 0;
    __syncthreads();
    sc_[tid] += t;
    __syncthreads();
  }
  int run = bsum[b] + sc_[tid] - s;
#pragma unroll
  for (int j = 0; j < 8; ++j) {
    if (base + j < nf) offsets[base + j] = run;
    run += loc[j];
  }
  if (b == gridDim.x - 1 && tid == 255) offsets[nf] = run;
}

// ---------------- main: fused GEMM + segment-avg + bias + relu + stats ----------------
__global__ __launch_bounds__(256) void k_main(
    const float* __restrict__ x, const float* __restrict__ bary,
    const float* __restrict__ W, const float* __restrict__ bias,
    const int* __restrict__ offsets, float* __restrict__ out,
    float* __restrict__ partials, int nf, int nblk)
{
  __shared__ short U[192 * 104];     // U-tile bf16, row pitch 104; aliased as y-tile f32 later
  __shared__ short W2[32 * 104];     // W transposed [o][k*32+c] bf16; aliased as reduce buf later
  __shared__ int off_s[65];

  const int tid = threadIdx.x;
  const int f0 = blockIdx.x * 64;

  // stage W2[o*104 + k*32 + c] = bf16(W[o*96 + c*3 + k])
  for (int idx = tid; idx < 3072; idx += 256) {
    int o = idx / 96;
    int ck = idx - o * 96;
    int k = ck >> 5, c = ck & 31;
    W2[o * 104 + ck] = f2bf(W[o * 96 + c * 3 + k]);
  }
  if (tid < 65) {
    int f = f0 + tid; if (f > nf) f = nf;
    off_s[tid] = offsets[f];
  }
  __syncthreads();

  const int base = off_s[0];
  const int S_total = off_s[64] - base;
  const int nch = (S_total + 191) / 192;

  float fsum[8];
#pragma unroll
  for (int i = 0; i < 8; ++i) fsum[i] = 0.f;

  const int lane = tid & 63;
  const int wv = tid >> 6;
  const int rowl = lane & 15;
  const int grp = lane >> 4;
  const int o_ep = tid & 31;
  const int g_ep = tid >> 5;

  for (int ch = 0; ch < nch; ++ch) {
    const int Srem = S_total - ch * 192;

    // ---- build U: U[r][k*32+c] = bf16(x[t][c] * b[t][k]) ----
#pragma unroll
    for (int it = 0; it < 6; ++it) {
      int idx = it * 256 + tid;        // 1536 tasks = 192 rows x 8 col-quads
      int r = idx >> 3, q = idx & 7;
      fv4 xv = {0.f, 0.f, 0.f, 0.f};
      float b0 = 0.f, b1 = 0.f, b2 = 0.f;
      if (r < Srem) {
        int t = base + ch * 192 + r;
        xv = *(const fv4*)(x + t * 32 + q * 4);
        b0 = bary[t * 3 + 0]; b1 = bary[t * 3 + 1]; b2 = bary[t * 3 + 2];
      }
      sv4 p0, p1, p2;
#pragma unroll
      for (int j = 0; j < 4; ++j) {
        p0[j] = f2bf(xv[j] * b0);
        p1[j] = f2bf(xv[j] * b1);
        p2[j] = f2bf(xv[j] * b2);
      }
      short* urow = &U[r * 104 + q * 4];
      *(sv4*)(urow)      = p0;
      *(sv4*)(urow + 32) = p1;
      *(sv4*)(urow + 64) = p2;
    }
    __syncthreads();

    // ---- MFMA: wave wv owns M-tiles {3wv..3wv+2}, N-tiles {0,1}, K=96 ----
    fv4 acc[3][2];
#pragma unroll
    for (int m = 0; m < 3; ++m)
#pragma unroll
      for (int n = 0; n < 2; ++n)
        acc[m][n] = (fv4){0.f, 0.f, 0.f, 0.f};

#pragma unroll
    for (int kb = 0; kb < 3; ++kb) {
      const int cko = kb * 32 + grp * 4;
      sv8 bf[2];
#pragma unroll
      for (int n = 0; n < 2; ++n) {
        const short* wrow = &W2[(n * 16 + rowl) * 104 + cko];
        sv4 lo = *(const sv4*)(wrow);
        sv4 hi = *(const sv4*)(wrow + 16);
#pragma unroll
        for (int j = 0; j < 4; ++j) { bf[n][j] = lo[j]; bf[n][4 + j] = hi[j]; }
      }
#pragma unroll
      for (int m = 0; m < 3; ++m) {
        const short* urow = &U[((wv * 3 + m) * 16 + rowl) * 104 + cko];
        sv4 lo = *(const sv4*)(urow);
        sv4 hi = *(const sv4*)(urow + 16);
        sv8 af;
#pragma unroll
        for (int j = 0; j < 4; ++j) { af[j] = lo[j]; af[4 + j] = hi[j]; }
        acc[m][0] = __builtin_amdgcn_mfma_f32_16x16x32_bf16(af, bf[0], acc[m][0], 0, 0, 0);
        acc[m][1] = __builtin_amdgcn_mfma_f32_16x16x32_bf16(af, bf[1], acc[m][1], 0, 0, 0);
      }
    }
    __syncthreads();   // all U reads done; safe to overwrite with y-tile

    // ---- y-tile to LDS (C layout: col = lane&15, row = (lane>>4)*4 + reg) ----
    float* yt = (float*)U;
#pragma unroll
    for (int m = 0; m < 3; ++m)
#pragma unroll
      for (int n = 0; n < 2; ++n)
#pragma unroll
        for (int r = 0; r < 4; ++r)
          yt[((wv * 3 + m) * 16 + grp * 4 + r) * 33 + n * 16 + rowl] = acc[m][n][r];
    __syncthreads();

    // ---- per-facet accumulate ----
#pragma unroll
    for (int i = 0; i < 8; ++i) {
      int fl = i * 8 + g_ep;
      int st = off_s[fl] - base - ch * 192;
      int nm = off_s[fl + 1] - off_s[fl];
      for (int j = 0; j < nm; ++j) {
        int lp = st + j;
        if (lp >= 0 && lp < 192) fsum[i] += yt[lp * 33 + o_ep];
      }
    }
    __syncthreads();   // before next chunk rebuilds U
  }

  // ---- finalize: avg + bias + relu, write pre-BN out, channel stats ----
  float bo = bias[o_ep];
  float s1 = 0.f, s2 = 0.f;
#pragma unroll
  for (int i = 0; i < 8; ++i) {
    int fl = i * 8 + g_ep;
    int f = f0 + fl;
    if (f < nf) {
      int nm = off_s[fl + 1] - off_s[fl];
      float v = fsum[i] / (float)(nm > 1 ? nm : 1) + bo;
      v = fmaxf(v, 0.f);
      out[f * 32 + o_ep] = v;
      s1 += v; s2 += v * v;
    }
  }
  __syncthreads();
  float* red = (float*)W2;     // 512 floats fit in W2's 6656 B
  red[tid] = s1;
  red[256 + tid] = s2;
  __syncthreads();
  if (tid < 32) {
    float a1 = 0.f, a2 = 0.f;
#pragma unroll
    for (int g = 0; g < 8; ++g) { a1 += red[g * 32 + tid]; a2 += red[256 + g * 32 + tid]; }
    partials[(long)tid * nblk + blockIdx.x]        = a1;
    partials[(long)(32 + tid) * nblk + blockIdx.x] = a2;
  }
}

// ---------------- reduce partials -> stats[64] (sum[32], sumsq[32]) ----------------
__global__ __launch_bounds__(256) void k_reduce(const float* __restrict__ partials,
                                                int nblk, float* __restrict__ stats) {
  __shared__ float sd[256];
  int c = blockIdx.x;
  const float* p = partials + (long)c * nblk;
  float s = 0.f;
  for (int i = threadIdx.x; i < nblk; i += 256) s += p[i];
  sd[threadIdx.x] = s; __syncthreads();
  for (int st = 128; st > 0; st >>= 1) {
    if (threadIdx.x < st) sd[threadIdx.x] += sd[threadIdx.x + st];
    __syncthreads();
  }
  if (threadIdx.x == 0) stats[c] = sd[0];
}

// ---------------- BN apply, in place on out ----------------
__global__ __launch_bounds__(256) void k_bn(float* __restrict__ out,
                                            const float* __restrict__ stats,
                                            const float* __restrict__ gamma,
                                            const float* __restrict__ beta, int nf) {
  __shared__ float sc[32], sh[32];
  if (threadIdx.x < 32) {
    int o = threadIdx.x;
    float inv_n = 1.0f / (float)nf;
    float mean = stats[o] * inv_n;
    float var = stats[32 + o] * inv_n - mean * mean;
    float rstd = rsqrtf(var + 1e-5f);
    float g = gamma[o] * rstd;
    sc[o] = g;
    sh[o] = beta[o] - mean * g;
  }
  __syncthreads();
  long total4 = (long)nf * 8;
  long idx0 = (long)blockIdx.x * 256 + threadIdx.x;
  int ob = ((int)idx0 & 7) * 4;           // constant per thread (stride % 8 == 0)
  fv4 scv = *(const fv4*)&sc[ob];
  fv4 shv = *(const fv4*)&sh[ob];
  for (long idx = idx0; idx < total4; idx += (long)gridDim.x * 256) {
    fv4 v = *((const fv4*)out + idx);
    v = v * scv + shv;
    *((fv4*)out + idx) = v;
  }
}

extern "C" void kernel_launch(void* const* d_in, const int* in_sizes, int n_in,
                              void* d_out, int out_size, void* d_ws, size_t ws_size,
                              hipStream_t stream) {
  const float* x     = (const float*)d_in[0];
  const float* bary  = (const float*)d_in[1];
  const int*   numt  = (const int*)d_in[2];
  const float* W     = (const float*)d_in[3];
  const float* bias  = (const float*)d_in[4];
  const float* gamma = (const float*)d_in[5];
  const float* beta  = (const float*)d_in[6];
  float* out = (float*)d_out;

  const int nf   = in_sizes[2];
  const int nblk = (nf + 63) / 64;
  const int nbS  = (nf + SCHUNK - 1) / SCHUNK;

  char* w = (char*)d_ws;
  int* offsets = (int*)w;
  size_t off1 = (4UL * (size_t)(nf + 1) + 255) & ~255UL;
  int* bsum = (int*)(w + off1);
  size_t off2 = (off1 + 4UL * (size_t)nbS + 255) & ~255UL;
  float* partials = (float*)(w + off2);
  size_t off3 = (off2 + 4UL * 64UL * (size_t)nblk + 255) & ~255UL;
  float* stats = (float*)(w + off3);

  scan1<<<nbS, 256, 0, stream>>>(numt, nf, bsum);
  scan2<<<1, 256, 0, stream>>>(bsum, nbS);
  scan3<<<nbS, 256, 0, stream>>>(numt, nf, bsum, offsets);
  k_main<<<nblk, 256, 0, stream>>>(x, bary, W, bias, offsets, out, partials, nf, nblk);
  k_reduce<<<64, 256, 0, stream>>>(partials, nblk, stats);
  k_bn<<<2048, 256, 0, stream>>>(out, stats, gamma, beta, nf);
}

// Round 4
// 181.887 us; speedup vs baseline: 1.0382x; 1.0382x over previous
//
#include <hip/hip_runtime.h>
#include <stdint.h>

typedef __attribute__((ext_vector_type(4))) float fv4;
typedef __attribute__((ext_vector_type(4))) short sv4;
typedef __attribute__((ext_vector_type(8))) short sv8;

#define SCHUNK 2048
#define FPB 128     // facets per block in k_main
#define PZ  108     // LDS row pitch (shorts)

static __device__ __forceinline__ short f2bf(float f) {
  union { float f; unsigned u; } v; v.f = f;
  unsigned u = v.u;
  u += 0x7fffu + ((u >> 16) & 1u);   // RNE to bf16
  return (short)(u >> 16);
}

// ---------------- scan: offsets from num_texture (R1-validated) ----------------
__global__ __launch_bounds__(256) void scan1(const int* __restrict__ num, int nf,
                                             int* __restrict__ bsum) {
  __shared__ int sd[256];
  int b = blockIdx.x, tid = threadIdx.x;
  int base = b * SCHUNK + tid * 8;
  int s = 0;
#pragma unroll
  for (int j = 0; j < 8; ++j) { int i = base + j; if (i < nf) s += num[i]; }
  sd[tid] = s; __syncthreads();
  for (int st = 128; st > 0; st >>= 1) {
    if (tid < st) sd[tid] += sd[tid + st];
    __syncthreads();
  }
  if (tid == 0) bsum[b] = sd[0];
}

__global__ __launch_bounds__(256) void scan2(int* __restrict__ bsum, int nb) {
  __shared__ int sd[256];
  int tid = threadIdx.x;
  int v = (tid < nb) ? bsum[tid] : 0;
  sd[tid] = v; __syncthreads();
  for (int off = 1; off < 256; off <<= 1) {
    int t = (tid >= off) ? sd[tid - off] : 0;
    __syncthreads();
    sd[tid] += t;
    __syncthreads();
  }
  if (tid < nb) bsum[tid] = sd[tid] - v;   // exclusive prefix
}

__global__ __launch_bounds__(256) void scan3(const int* __restrict__ num, int nf,
                                             const int* __restrict__ bsum,
                                             int* __restrict__ offsets) {
  __shared__ int sc_[256];
  int b = blockIdx.x, tid = threadIdx.x;
  int base = b * SCHUNK + tid * 8;
  int loc[8]; int s = 0;
#pragma unroll
  for (int j = 0; j < 8; ++j) {
    loc[j] = (base + j < nf) ? num[base + j] : 0;
    s += loc[j];
  }
  sc_[tid] = s; __syncthreads();
  for (int off = 1; off < 256; off <<= 1) {
    int t = (tid >= off) ? sc_[tid - off] : 0;
    __syncthreads();
    sc_[tid] += t;
    __syncthreads();
  }
  int run = bsum[b] + sc_[tid] - s;
#pragma unroll
  for (int j = 0; j < 8; ++j) {
    if (base + j < nf) offsets[base + j] = run;
    run += loc[j];
  }
  if (b == gridDim.x - 1 && tid == 255) offsets[nf] = run;
}

// ---------------- main: segsum(x*b) -> GEMM -> yt(LDS) -> avg+bias+relu + stats ----------------
// Z[f, k*32+c] = sum_{s in facet f} x[s,c]*b[s,k]   (fp32 accum, stored bf16)
// out[f,o] = relu( (1/n_f) * sum_{ck} Z[f,ck]*W2[o,ck] + bias[o] )
__global__ __launch_bounds__(256) void k_main(
    const float* __restrict__ x, const float* __restrict__ bary,
    const float* __restrict__ W, const float* __restrict__ bias,
    const int* __restrict__ offsets, float* __restrict__ out,
    float* __restrict__ partials, int nf, int nblk)
{
  __shared__ short Z[FPB * PZ];        // 27648 B; aliased as float yt[128*33] after GEMM
  __shared__ short W2[32 * PZ];        // 6912 B; aliased as float red[512] at finalize
  __shared__ int off_s[FPB + 1];

  const int tid = threadIdx.x;
  const int f0 = blockIdx.x * FPB;

  // stage W2[o*PZ + k*32 + c] = bf16(W[o*96 + c*3 + k])   (R1-validated)
  for (int idx = tid; idx < 3072; idx += 256) {
    int o = idx / 96;
    int ck = idx - o * 96;
    int k = ck >> 5, c = ck & 31;
    W2[o * PZ + ck] = f2bf(W[o * 96 + c * 3 + k]);
  }
  for (int i = tid; i < FPB + 1; i += 256) {
    int f = f0 + i; if (f > nf) f = nf;
    off_s[i] = offsets[f];
  }
  __syncthreads();

  // ---- build Z: SCALAR, one task per (facet, channel): 128*32 = 4096 tasks ----
  for (int idx = tid; idx < 4096; idx += 256) {
    int fl = idx >> 5, c = idx & 31;         // consecutive lanes -> consecutive channels (coalesced x)
    int st = off_s[fl], en = off_s[fl + 1];
    float z0 = 0.f, z1 = 0.f, z2 = 0.f;
    for (int t = st; t < en; ++t) {
      float xv = x[t * 32 + c];
      float b0 = bary[t * 3 + 0];
      float b1 = bary[t * 3 + 1];
      float b2 = bary[t * 3 + 2];
      z0 += xv * b0;
      z1 += xv * b1;
      z2 += xv * b2;
    }
    Z[fl * PZ + c]      = f2bf(z0);
    Z[fl * PZ + 32 + c] = f2bf(z1);
    Z[fl * PZ + 64 + c] = f2bf(z2);
  }
  __syncthreads();

  // ---- GEMM: M=128 (facets), N=32, K=96; 4 waves x 2 M-tiles x 2 N-tiles (R1-validated addressing) ----
  const int lane = tid & 63;
  const int wv = tid >> 6;
  const int rowl = lane & 15;
  const int grp = lane >> 4;

  fv4 acc[2][2];
#pragma unroll
  for (int m = 0; m < 2; ++m)
#pragma unroll
    for (int n = 0; n < 2; ++n)
      acc[m][n] = (fv4){0.f, 0.f, 0.f, 0.f};

#pragma unroll
  for (int kb = 0; kb < 3; ++kb) {
    const int cko = kb * 32 + grp * 4;
    sv8 bfr[2];
#pragma unroll
    for (int n = 0; n < 2; ++n) {
      const short* wr = &W2[(n * 16 + rowl) * PZ + cko];
      sv4 lo = *(const sv4*)(wr);
      sv4 hi = *(const sv4*)(wr + 16);
#pragma unroll
      for (int j = 0; j < 4; ++j) { bfr[n][j] = lo[j]; bfr[n][4 + j] = hi[j]; }
    }
#pragma unroll
    for (int m = 0; m < 2; ++m) {
      const short* zr = &Z[(wv * 32 + m * 16 + rowl) * PZ + cko];
      sv4 lo = *(const sv4*)(zr);
      sv4 hi = *(const sv4*)(zr + 16);
      sv8 afr;
#pragma unroll
      for (int j = 0; j < 4; ++j) { afr[j] = lo[j]; afr[4 + j] = hi[j]; }
      acc[m][0] = __builtin_amdgcn_mfma_f32_16x16x32_bf16(afr, bfr[0], acc[m][0], 0, 0, 0);
      acc[m][1] = __builtin_amdgcn_mfma_f32_16x16x32_bf16(afr, bfr[1], acc[m][1], 0, 0, 0);
    }
  }
  __syncthreads();              // all Z reads done; safe to alias as yt

  // ---- y-tile to LDS with R1-validated C-write formula ----
  float* yt = (float*)Z;        // 128 x 33 floats = 16896 B
#pragma unroll
  for (int m = 0; m < 2; ++m)
#pragma unroll
    for (int n = 0; n < 2; ++n)
#pragma unroll
      for (int r = 0; r < 4; ++r)
        yt[(wv * 32 + m * 16 + grp * 4 + r) * 33 + n * 16 + rowl] = acc[m][n][r];
  __syncthreads();

  // ---- finalize with R1-validated pattern: avg + bias + relu, out, stats ----
  const int o_ep = tid & 31;
  const int g_ep = tid >> 5;
  float bo = bias[o_ep];
  float s1 = 0.f, s2 = 0.f;
#pragma unroll
  for (int i = 0; i < 16; ++i) {
    int fl = i * 8 + g_ep;
    int f = f0 + fl;
    if (f < nf) {
      int nm = off_s[fl + 1] - off_s[fl];
      float v = yt[fl * 33 + o_ep] / (float)(nm > 1 ? nm : 1) + bo;
      v = fmaxf(v, 0.f);
      out[f * 32 + o_ep] = v;
      s1 += v; s2 += v * v;
    }
  }
  __syncthreads();              // W2 reads long done; safe to alias as red
  float* red = (float*)W2;      // 512 floats = 2048 B
  red[tid] = s1;
  red[256 + tid] = s2;
  __syncthreads();
  if (tid < 32) {
    float a1 = 0.f, a2 = 0.f;
#pragma unroll
    for (int g = 0; g < 8; ++g) { a1 += red[g * 32 + tid]; a2 += red[256 + g * 32 + tid]; }
    partials[(long)tid * nblk + blockIdx.x]        = a1;
    partials[(long)(32 + tid) * nblk + blockIdx.x] = a2;
  }
}

// ---------------- reduce partials -> stats[64] (sum[32], sumsq[32]) ----------------
__global__ __launch_bounds__(256) void k_reduce(const float* __restrict__ partials,
                                                int nblk, float* __restrict__ stats) {
  __shared__ float sd[256];
  int c = blockIdx.x;
  const float* p = partials + (long)c * nblk;
  float s = 0.f;
  for (int i = threadIdx.x; i < nblk; i += 256) s += p[i];
  sd[threadIdx.x] = s; __syncthreads();
  for (int st = 128; st > 0; st >>= 1) {
    if (threadIdx.x < st) sd[threadIdx.x] += sd[threadIdx.x + st];
    __syncthreads();
  }
  if (threadIdx.x == 0) stats[c] = sd[0];
}

// ---------------- BN apply, in place on out ----------------
__global__ __launch_bounds__(256) void k_bn(float* __restrict__ out,
                                            const float* __restrict__ stats,
                                            const float* __restrict__ gamma,
                                            const float* __restrict__ beta, int nf) {
  __shared__ float sc[32], sh[32];
  if (threadIdx.x < 32) {
    int o = threadIdx.x;
    float inv_n = 1.0f / (float)nf;
    float mean = stats[o] * inv_n;
    float var = stats[32 + o] * inv_n - mean * mean;
    float rstd = rsqrtf(var + 1e-5f);
    float g = gamma[o] * rstd;
    sc[o] = g;
    sh[o] = beta[o] - mean * g;
  }
  __syncthreads();
  long total4 = (long)nf * 8;
  long idx0 = (long)blockIdx.x * 256 + threadIdx.x;
  int ob = ((int)idx0 & 7) * 4;           // constant per thread (stride % 8 == 0)
  fv4 scv = *(const fv4*)&sc[ob];
  fv4 shv = *(const fv4*)&sh[ob];
  for (long idx = idx0; idx < total4; idx += (long)gridDim.x * 256) {
    fv4 v = *((const fv4*)out + idx);
    v = v * scv + shv;
    *((fv4*)out + idx) = v;
  }
}

extern "C" void kernel_launch(void* const* d_in, const int* in_sizes, int n_in,
                              void* d_out, int out_size, void* d_ws, size_t ws_size,
                              hipStream_t stream) {
  const float* x     = (const float*)d_in[0];
  const float* bary  = (const float*)d_in[1];
  const int*   numt  = (const int*)d_in[2];
  const float* W     = (const float*)d_in[3];
  const float* bias  = (const float*)d_in[4];
  const float* gamma = (const float*)d_in[5];
  const float* beta  = (const float*)d_in[6];
  float* out = (float*)d_out;

  const int nf   = in_sizes[2];
  const int nblk = (nf + FPB - 1) / FPB;
  const int nbS  = (nf + SCHUNK - 1) / SCHUNK;

  char* w = (char*)d_ws;
  int* offsets = (int*)w;
  size_t off1 = (4UL * (size_t)(nf + 1) + 255) & ~255UL;
  int* bsum = (int*)(w + off1);
  size_t off2 = (off1 + 4UL * (size_t)nbS + 255) & ~255UL;
  float* partials = (float*)(w + off2);
  size_t off3 = (off2 + 4UL * 64UL * (size_t)nblk + 255) & ~255UL;
  float* stats = (float*)(w + off3);

  scan1<<<nbS, 256, 0, stream>>>(numt, nf, bsum);
  scan2<<<1, 256, 0, stream>>>(bsum, nbS);
  scan3<<<nbS, 256, 0, stream>>>(numt, nf, bsum, offsets);
  k_main<<<nblk, 256, 0, stream>>>(x, bary, W, bias, offsets, out, partials, nf, nblk);
  k_reduce<<<64, 256, 0, stream>>>(partials, nblk, stats);
  k_bn<<<2048, 256, 0, stream>>>(out, stats, gamma, beta, nf);
}